// Round 12
// baseline (207.098 us; speedup 1.0000x reference)
//
#include <hip/hip_runtime.h>
#include <hip/hip_bf16.h>

#define D 128      // D_IN == D_OUT
#define SH 7       // log2 rows per bucket
#define BROWS 128  // rows per bucket
#define NBK_MAX 1024
#define CT 8       // col tiles (128/16)
#define KS 4       // k steps   (128/32)

typedef __bf16   bf16x8 __attribute__((ext_vector_type(8)));
typedef float    f32x4  __attribute__((ext_vector_type(4)));
typedef _Float16 f16x2  __attribute__((ext_vector_type(2)));
typedef _Float16 f16x4  __attribute__((ext_vector_type(4)));
typedef _Float16 f16x8  __attribute__((ext_vector_type(8)));

// ===========================================================================
// CSR build (bucketed)
// ===========================================================================
__global__ __launch_bounds__(256) void k_zero(int* __restrict__ p, int n) {
    for (int i = blockIdx.x * blockDim.x + threadIdx.x; i < n; i += gridDim.x * blockDim.x)
        p[i] = 0;
}

__global__ __launch_bounds__(256) void k_bucket_count(const int* __restrict__ rows,
                                                      int* __restrict__ bcnt, int E, int NBK) {
    __shared__ int h[NBK_MAX];
    for (int i = threadIdx.x; i < NBK; i += 256) h[i] = 0;
    __syncthreads();
    for (int e = blockIdx.x * blockDim.x + threadIdx.x; e < E; e += gridDim.x * blockDim.x)
        atomicAdd(&h[rows[e] >> SH], 1);
    __syncthreads();
    for (int i = threadIdx.x; i < NBK; i += 256) {
        int v = h[i];
        if (v) atomicAdd(&bcnt[i], v);
    }
}

__global__ __launch_bounds__(1024) void k_scan_buckets(const int* __restrict__ bcnt,
                                                       int* __restrict__ boff,
                                                       int* __restrict__ bcur,
                                                       int* __restrict__ row_start,
                                                       int NBK, int N, int E) {
    __shared__ int sd[1024];
    int t = threadIdx.x;
    int own = (t < NBK) ? bcnt[t] : 0;
    sd[t] = own;
    __syncthreads();
    for (int off = 1; off < 1024; off <<= 1) {
        int add = (t >= off) ? sd[t - off] : 0;
        __syncthreads();
        sd[t] += add;
        __syncthreads();
    }
    if (t < NBK) {
        int ex = sd[t] - own;
        boff[t] = ex;
        bcur[t] = ex;
    }
    if (t == 0) {
        boff[NBK] = E;
        row_start[N] = E;
    }
}

__global__ __launch_bounds__(256) void k_pairs(const int* __restrict__ rows,
                                               const int* __restrict__ cols,
                                               int* __restrict__ bcur,
                                               unsigned* __restrict__ pairs,
                                               int E, int NBK, int chunk) {
    __shared__ int h[NBK_MAX];
    int e0 = blockIdx.x * chunk;
    if (e0 >= E) return;
    int e1 = min(E, e0 + chunk);
    for (int i = threadIdx.x; i < NBK; i += 256) h[i] = 0;
    __syncthreads();
    for (int e = e0 + threadIdx.x; e < e1; e += 256)
        atomicAdd(&h[rows[e] >> SH], 1);
    __syncthreads();
    for (int b = threadIdx.x; b < NBK; b += 256) {
        int v = h[b];
        h[b] = v ? atomicAdd(&bcur[b], v) : 0;
    }
    __syncthreads();
    for (int e = e0 + threadIdx.x; e < e1; e += 256) {
        int r = rows[e];
        int b = r >> SH;
        int p = atomicAdd(&h[b], 1);
        pairs[p] = ((unsigned)(r & (BROWS - 1)) << 24) | (unsigned)cols[e];
    }
}

// per-bucket (128 rows, 128 threads): hist -> scan -> row_start/dr -> place
__global__ __launch_bounds__(128) void k_bucket_finish(const unsigned* __restrict__ pairs,
                                                       const int* __restrict__ boff,
                                                       int* __restrict__ row_start,
                                                       float* __restrict__ dr,
                                                       int* __restrict__ csr_col, int N) {
    __shared__ int h[BROWS];
    __shared__ int cur[BROWS];
    int b = blockIdx.x;
    int t = threadIdx.x;                 // 0..127
    int lim = min(N - (b << SH), BROWS);
    h[t] = 0;
    __syncthreads();
    int p0 = boff[b], p1 = boff[b + 1];
    for (int p = p0 + t; p < p1; p += 128)
        atomicAdd(&h[pairs[p] >> 24], 1);
    __syncthreads();
    int own = h[t];
    cur[t] = own;
    __syncthreads();
    for (int off = 1; off < 128; off <<= 1) {
        int add = (t >= off) ? cur[t - off] : 0;
        __syncthreads();
        cur[t] += add;
        __syncthreads();
    }
    int rs = p0 + cur[t] - own;
    if (t < lim) {
        row_start[(b << SH) + t] = rs;
        dr[(b << SH) + t] = rsqrtf((float)(own + 1));
    }
    __syncthreads();
    cur[t] = rs;
    __syncthreads();
    for (int p = p0 + t; p < p1; p += 128) {
        unsigned v = pairs[p];
        int q = atomicAdd(&cur[v >> 24], 1);
        csr_col[q] = (int)(v & 0xFFFFFF);
    }
}

// merged prep: blocks 0..7 also pack W->f16 fragments; all blocks stream
// x (fp32) -> xh (fp16) pre-scaled by dr.
__global__ __launch_bounds__(256) void k_prep(const float4* __restrict__ x4,
                                              const float* __restrict__ dr,
                                              f16x4* __restrict__ xh4, int n4,
                                              const float* __restrict__ W,
                                              f16x8* __restrict__ Whi) {
    if (blockIdx.x < 8) {
        int f = blockIdx.x * 256 + threadIdx.x;   // 2048 fragments
        int l  = f & 63;
        int ks = (f >> 6) & 3;
        int ct = f >> 8;
        int o  = ct * 16 + (l & 15);
        int k0 = ks * 32 + ((l >> 4) * 8);
        const float* src = &W[o * D + k0];
        f16x8 hi;
#pragma unroll
        for (int i = 0; i < 8; ++i) hi[i] = (_Float16)src[i];
        Whi[f] = hi;
    }
    for (int i = blockIdx.x * blockDim.x + threadIdx.x; i < n4; i += gridDim.x * blockDim.x) {
        float d = dr[i >> 5];   // 32 float4 per row
        float4 v = x4[i];
        xh4[i] = (f16x4){(_Float16)(v.x * d), (_Float16)(v.y * d),
                         (_Float16)(v.z * d), (_Float16)(v.w * d)};
    }
}

// ===========================================================================
// wide gather: lane l = d-chunk (l&15)*8 of edge-slot l>>4.
// One f16x8 load instruction covers 4 edges (1 KB). 16 edges per main iter.
// agg f16 written into first 256 B of each 512 B out-row slot.
// ===========================================================================
__global__ __launch_bounds__(256) void k_gather_w(const int* __restrict__ row_start,
                                                  const int* __restrict__ csr_col,
                                                  const _Float16* __restrict__ xh,
                                                  const float* __restrict__ dr,
                                                  _Float16* __restrict__ aggh, int N) {
    int lane  = threadIdx.x & 63;
    int eslot = lane >> 4;          // 0..3
    int dbase = (lane & 15) * 8;    // half offset of this lane's d-chunk
    int gw = (blockIdx.x * blockDim.x + threadIdx.x) >> 6;
    int nw = (gridDim.x * blockDim.x) >> 6;
    for (int r = gw; r < N; r += nw) {
        int beg = row_start[r], end = row_start[r + 1];
        float drr = dr[r];
        float acc[8];
        if (eslot == 0) {
            f16x8 xs = *(const f16x8*)&xh[(size_t)r * D + dbase];
#pragma unroll
            for (int i = 0; i < 8; ++i) acc[i] = (float)xs[i];
        } else {
#pragma unroll
            for (int i = 0; i < 8; ++i) acc[i] = 0.f;
        }
        for (int cb = beg; cb < end; cb += 64) {
            int m = end - cb;
            if (m > 64) m = 64;
            int cidx = (lane < m) ? csr_col[cb + lane] : 0;
            int g = 0;
            for (; g + 16 <= m; g += 16) {
                int c0 = __shfl(cidx, g + eslot);
                int c1 = __shfl(cidx, g + 4 + eslot);
                int c2 = __shfl(cidx, g + 8 + eslot);
                int c3 = __shfl(cidx, g + 12 + eslot);
                f16x8 p0 = *(const f16x8*)&xh[(size_t)c0 * D + dbase];
                f16x8 p1 = *(const f16x8*)&xh[(size_t)c1 * D + dbase];
                f16x8 p2 = *(const f16x8*)&xh[(size_t)c2 * D + dbase];
                f16x8 p3 = *(const f16x8*)&xh[(size_t)c3 * D + dbase];
#pragma unroll
                for (int i = 0; i < 8; ++i)
                    acc[i] += ((float)p0[i] + (float)p1[i]) + ((float)p2[i] + (float)p3[i]);
            }
            for (; g < m; g += 4) {
                int srcl = g + eslot;
                bool valid = srcl < m;
                int c = __shfl(cidx, valid ? srcl : 0);
                if (valid) {
                    f16x8 pv = *(const f16x8*)&xh[(size_t)c * D + dbase];
#pragma unroll
                    for (int i = 0; i < 8; ++i) acc[i] += (float)pv[i];
                }
            }
        }
#pragma unroll
        for (int i = 0; i < 8; ++i) {
            acc[i] += __shfl_xor(acc[i], 16);
            acc[i] += __shfl_xor(acc[i], 32);
        }
        if (lane < 16) {
            f16x8 o;
#pragma unroll
            for (int i = 0; i < 8; ++i) o[i] = (_Float16)(drr * acc[i]);
            *(f16x8*)&aggh[(size_t)r * 256 + dbase] = o;
        }
    }
}

// ===========================================================================
// projection + relu: f16 MFMA (W single-f16), A from out slots, B from
// global L2-hot 32 KB; no LDS -> high occupancy. 32 MFMA / 16-row tile.
// ===========================================================================
__global__ __launch_bounds__(256) void k_project_g(const f16x8* __restrict__ Whi,
                                                   float* __restrict__ out, int N) {
    const _Float16* ah = (const _Float16*)out;
    int lane = threadIdx.x & 63;
    int wib  = threadIdx.x >> 6;
    int gw   = blockIdx.x * 4 + wib;
    int nw   = gridDim.x * 4;
    int nt   = N >> 4;
    int arow  = lane & 15;
    int kbase = (lane >> 4) * 8;

    for (int t = gw; t < nt; t += nw) {
        int row = t * 16 + arow;
        f16x8 A[KS];
#pragma unroll
        for (int ks = 0; ks < KS; ++ks)
            A[ks] = *(const f16x8*)&ah[(size_t)row * 256 + ks * 32 + kbase];

        f32x4 acc[CT];
#pragma unroll
        for (int ct = 0; ct < CT; ++ct) acc[ct] = (f32x4){0.f, 0.f, 0.f, 0.f};
#pragma unroll
        for (int ks = 0; ks < KS; ++ks) {
#pragma unroll
            for (int ct = 0; ct < CT; ++ct) {
                f16x8 bh = Whi[(ct * KS + ks) * 64 + lane];
                acc[ct] = __builtin_amdgcn_mfma_f32_16x16x32_f16(A[ks], bh, acc[ct], 0, 0, 0);
            }
        }
        int orow = t * 16 + (lane >> 4) * 4;
        int ocol = lane & 15;
#pragma unroll
        for (int ct = 0; ct < CT; ++ct) {
#pragma unroll
            for (int reg = 0; reg < 4; ++reg) {
                out[(size_t)(orow + reg) * D + ct * 16 + ocol] = fmaxf(acc[ct][reg], 0.f);
            }
        }
    }
}

// ===========================================================================
// mid-tier fallback: fp32 gather + LDS bf16-split project
// ===========================================================================
__global__ __launch_bounds__(256) void k_gather(const int* __restrict__ row_start,
                                                const int* __restrict__ csr_col,
                                                const float* __restrict__ x,
                                                const float* __restrict__ dr,
                                                float* __restrict__ out, int N) {
    int lane = threadIdx.x & 63;
    int gw = (blockIdx.x * blockDim.x + threadIdx.x) >> 6;
    int nw = (gridDim.x * blockDim.x) >> 6;
    for (int r = gw; r < N; r += nw) {
        float drr = dr[r];
        int beg = row_start[r], end = row_start[r + 1];
        const float2 xs = *(const float2*)&x[(size_t)r * D + lane * 2];
        float s = drr * drr;
        float a0 = s * xs.x, a1 = s * xs.y;
        for (int cb = beg; cb < end; cb += 64) {
            int m = end - cb;
            if (m > 64) m = 64;
            int   cidx = (lane < m) ? csr_col[cb + lane] : 0;
            float cdr  = (lane < m) ? dr[cidx] : 0.f;
            int j = 0;
            for (; j + 4 <= m; j += 4) {
                int c0 = __shfl(cidx, j);
                int c1 = __shfl(cidx, j + 1);
                int c2 = __shfl(cidx, j + 2);
                int c3 = __shfl(cidx, j + 3);
                float v0 = drr * __shfl(cdr, j);
                float v1 = drr * __shfl(cdr, j + 1);
                float v2 = drr * __shfl(cdr, j + 2);
                float v3 = drr * __shfl(cdr, j + 3);
                const float2 p0 = *(const float2*)&x[(size_t)c0 * D + lane * 2];
                const float2 p1 = *(const float2*)&x[(size_t)c1 * D + lane * 2];
                const float2 p2 = *(const float2*)&x[(size_t)c2 * D + lane * 2];
                const float2 p3 = *(const float2*)&x[(size_t)c3 * D + lane * 2];
                a0 = fmaf(v0, p0.x, a0); a1 = fmaf(v0, p0.y, a1);
                a0 = fmaf(v1, p1.x, a0); a1 = fmaf(v1, p1.y, a1);
                a0 = fmaf(v2, p2.x, a0); a1 = fmaf(v2, p2.y, a1);
                a0 = fmaf(v3, p3.x, a0); a1 = fmaf(v3, p3.y, a1);
            }
            for (; j < m; ++j) {
                int   c = __shfl(cidx, j);
                float v = drr * __shfl(cdr, j);
                const float2 p = *(const float2*)&x[(size_t)c * D + lane * 2];
                a0 = fmaf(v, p.x, a0);
                a1 = fmaf(v, p.y, a1);
            }
        }
        float2 o;
        o.x = a0;
        o.y = a1;
        *(float2*)&out[(size_t)r * D + lane * 2] = o;
    }
}

__global__ __launch_bounds__(256) void k_project_mfma(const float* __restrict__ W,
                                                      float* __restrict__ out, int N) {
    __shared__ bf16x8 Bhi[CT * KS * 64];
    __shared__ bf16x8 Blo[CT * KS * 64];
    for (int f = threadIdx.x; f < CT * KS * 64; f += 256) {
        int l  = f & 63;
        int ks = (f >> 6) & 3;
        int ct = f >> 8;
        int o  = ct * 16 + (l & 15);
        int k0 = ks * 32 + ((l >> 4) * 8);
        const float* src = &W[o * D + k0];
        bf16x8 hi, lo;
#pragma unroll
        for (int i = 0; i < 8; ++i) {
            float v  = src[i];
            __bf16 h = (__bf16)v;
            hi[i] = h;
            lo[i] = (__bf16)(v - (float)h);
        }
        Bhi[f] = hi;
        Blo[f] = lo;
    }
    __syncthreads();

    int lane = threadIdx.x & 63;
    int wib  = threadIdx.x >> 6;
    int gw   = blockIdx.x * 4 + wib;
    int nw   = gridDim.x * 4;
    int nt   = N >> 4;
    int arow  = lane & 15;
    int kbase = (lane >> 4) * 8;

    for (int t = gw; t < nt; t += nw) {
        int row = t * 16 + arow;
        const float* arp = &out[(size_t)row * D + kbase];
        bf16x8 Ahi[KS], Alo[KS];
#pragma unroll
        for (int ks = 0; ks < KS; ++ks) {
            float4 v0 = *(const float4*)&arp[ks * 32];
            float4 v1 = *(const float4*)&arp[ks * 32 + 4];
            float va[8] = {v0.x, v0.y, v0.z, v0.w, v1.x, v1.y, v1.z, v1.w};
            bf16x8 hi, lo;
#pragma unroll
            for (int i = 0; i < 8; ++i) {
                __bf16 h = (__bf16)va[i];
                hi[i] = h;
                lo[i] = (__bf16)(va[i] - (float)h);
            }
            Ahi[ks] = hi;
            Alo[ks] = lo;
        }
        f32x4 acc[CT];
#pragma unroll
        for (int ct = 0; ct < CT; ++ct) acc[ct] = (f32x4){0.f, 0.f, 0.f, 0.f};
#pragma unroll
        for (int ks = 0; ks < KS; ++ks) {
#pragma unroll
            for (int ct = 0; ct < CT; ++ct) {
                bf16x8 bh = Bhi[(ct * KS + ks) * 64 + lane];
                bf16x8 bl = Blo[(ct * KS + ks) * 64 + lane];
                acc[ct] = __builtin_amdgcn_mfma_f32_16x16x32_bf16(Ahi[ks], bh, acc[ct], 0, 0, 0);
                acc[ct] = __builtin_amdgcn_mfma_f32_16x16x32_bf16(Alo[ks], bh, acc[ct], 0, 0, 0);
                acc[ct] = __builtin_amdgcn_mfma_f32_16x16x32_bf16(Ahi[ks], bl, acc[ct], 0, 0, 0);
            }
        }
        int orow = t * 16 + (lane >> 4) * 4;
        int ocol = lane & 15;
#pragma unroll
        for (int ct = 0; ct < CT; ++ct) {
#pragma unroll
            for (int reg = 0; reg < 4; ++reg) {
                out[(size_t)(orow + reg) * D + ct * 16 + ocol] = fmaxf(acc[ct][reg], 0.f);
            }
        }
    }
}

// ===========================================================================
// last-resort fallback (atomic path)
// ===========================================================================
__global__ __launch_bounds__(256) void k_init_deg(int* __restrict__ deg, int n) {
    for (int i = blockIdx.x * blockDim.x + threadIdx.x; i < n; i += gridDim.x * blockDim.x)
        deg[i] = 1;
}
__global__ __launch_bounds__(256) void k_count_atomic(const int* __restrict__ rows,
                                                      int* __restrict__ cnt, int E) {
    for (int e = blockIdx.x * blockDim.x + threadIdx.x; e < E; e += gridDim.x * blockDim.x)
        atomicAdd(&cnt[rows[e]], 1);
}
__global__ __launch_bounds__(256) void k_rsqrt(float* __restrict__ buf, int n) {
    const int* di = (const int*)buf;
    for (int i = blockIdx.x * blockDim.x + threadIdx.x; i < n; i += gridDim.x * blockDim.x) {
        int v = di[i];
        buf[i] = rsqrtf((float)v);
    }
}
__global__ __launch_bounds__(256) void k_init_out(const float4* __restrict__ x4,
                                                  const float* __restrict__ dr,
                                                  float4* __restrict__ out4, int n4) {
    for (int i = blockIdx.x * blockDim.x + threadIdx.x; i < n4; i += gridDim.x * blockDim.x) {
        float d = dr[i >> 5];
        float s = d * d;
        float4 v = x4[i];
        out4[i] = make_float4(v.x * s, v.y * s, v.z * s, v.w * s);
    }
}
__global__ __launch_bounds__(256) void k_edges(const int* __restrict__ rows,
                                               const int* __restrict__ cols,
                                               const float* __restrict__ x,
                                               const float* __restrict__ dr,
                                               float* __restrict__ out, int E) {
    int lane = threadIdx.x & 63;
    int wib  = threadIdx.x >> 6;
    int gw   = blockIdx.x * 4 + wib;
    int nw   = gridDim.x * 4;
    for (int e = gw; e < E; e += nw) {
        int r = rows[e];
        int c = cols[e];
        float val = dr[r] * dr[c];
        const float2 xv = *(const float2*)&x[(size_t)c * D + lane * 2];
        float* po = &out[(size_t)r * D + lane * 2];
        unsafeAtomicAdd(po,     val * xv.x);
        unsafeAtomicAdd(po + 1, val * xv.y);
    }
}

// ===========================================================================
extern "C" void kernel_launch(void* const* d_in, const int* in_sizes, int n_in,
                              void* d_out, int out_size, void* d_ws, size_t ws_size,
                              hipStream_t stream) {
    const float* x   = (const float*)d_in[0];
    const int*   idx = (const int*)d_in[1];
    const float* W   = (const float*)d_in[2];
    float*       out = (float*)d_out;

    int N = in_sizes[0] / D;   // 100000
    int E = in_sizes[1] / 2;   // 1.6M
    const int* rows = idx;
    const int* cols = idx + E;

    int NBK = (N + BROWS - 1) >> SH;   // 782

    // workspace layout in 4B words
    size_t off = 0;
    size_t o_pairs = off;  off += (size_t)E;
    size_t o_csr   = off;  off += (size_t)E;
    size_t o_rs    = off;  off += (size_t)N + 1;
    size_t o_dr    = off;  off += (size_t)N;
    size_t o_bcnt  = off;  off += (size_t)NBK;
    size_t o_boff  = off;  off += (size_t)NBK + 1;
    size_t o_bcur  = off;  off += (size_t)NBK;
    off = (off + 3) & ~(size_t)3;      // 16B align
    size_t need_mid = off * 4;
    size_t o_whi   = off;  off += (size_t)(CT * KS * 64) * 4;   // f16x8 = 4 words
    size_t o_xh    = off;  off += ((size_t)N * D) / 2;          // halves = words/2
    size_t need_full = off * 4;

    int* wsw = (int*)d_ws;
    bool shape_ok = (NBK <= NBK_MAX) && ((N & 15) == 0) && (N < (1 << 24));

    if (shape_ok && ws_size >= need_mid) {
        unsigned* pairs     = (unsigned*)(wsw + o_pairs);
        int*      csr_col   = wsw + o_csr;
        int*      row_start = wsw + o_rs;
        float*    dr        = (float*)(wsw + o_dr);
        int*      bcnt      = wsw + o_bcnt;
        int*      boff      = wsw + o_boff;
        int*      bcur      = wsw + o_bcur;

        const int CHUNK = 2048;        // 782 WGs in k_pairs
        k_zero<<<(NBK + 255) / 256, 256, 0, stream>>>(bcnt, NBK);
        k_bucket_count<<<512, 256, 0, stream>>>(rows, bcnt, E, NBK);
        k_scan_buckets<<<1, 1024, 0, stream>>>(bcnt, boff, bcur, row_start, NBK, N, E);
        k_pairs<<<(E + CHUNK - 1) / CHUNK, 256, 0, stream>>>(rows, cols, bcur, pairs,
                                                             E, NBK, CHUNK);
        k_bucket_finish<<<NBK, 128, 0, stream>>>(pairs, boff, row_start, dr, csr_col, N);

        if (ws_size >= need_full) {
            f16x8*    Whi = (f16x8*)(wsw + o_whi);
            _Float16* xh  = (_Float16*)(wsw + o_xh);
            k_prep<<<2048, 256, 0, stream>>>((const float4*)x, dr, (f16x4*)xh, N * (D / 4),
                                             W, Whi);
            _Float16* aggh = (_Float16*)out;
            k_gather_w<<<4096, 256, 0, stream>>>(row_start, csr_col, xh, dr, aggh, N);
            int nt = N >> 4;
            k_project_g<<<(nt + 3) / 4, 256, 0, stream>>>(Whi, out, N);
        } else {
            k_gather<<<4096, 256, 0, stream>>>(row_start, csr_col, x, dr, out, N);
            int nt = N >> 4;
            k_project_mfma<<<(nt + 3) / 4, 256, 0, stream>>>(W, out, N);
        }
    } else {
        int*   deg = (int*)d_ws;
        float* dr  = (float*)d_ws;
        k_init_deg<<<(N + 255) / 256, 256, 0, stream>>>(deg, N);
        k_count_atomic<<<2048, 256, 0, stream>>>(rows, deg, E);
        k_rsqrt<<<(N + 255) / 256, 256, 0, stream>>>(dr, N);
        int n4 = N * (D / 4);
        k_init_out<<<4096, 256, 0, stream>>>((const float4*)x, dr, (float4*)out, n4);
        k_edges<<<4096, 256, 0, stream>>>(rows, cols, x, dr, out, E);
        int nt = N >> 4;
        k_project_mfma<<<(nt + 3) / 4, 256, 0, stream>>>(W, out, N);
    }
}

// Round 13
// 192.053 us; speedup vs baseline: 1.0783x; 1.0783x over previous
//
#include <hip/hip_runtime.h>
#include <hip/hip_bf16.h>

#define D 128      // D_IN == D_OUT
#define SH 8       // log2 rows per bucket
#define BROWS 256  // rows per bucket
#define NBK_MAX 512
#define CT 8       // col tiles (128/16)
#define KS 4       // k steps   (128/32)

typedef __bf16   bf16x8 __attribute__((ext_vector_type(8)));
typedef float    f32x4  __attribute__((ext_vector_type(4)));
typedef _Float16 f16x2  __attribute__((ext_vector_type(2)));
typedef _Float16 f16x4  __attribute__((ext_vector_type(4)));
typedef _Float16 f16x8  __attribute__((ext_vector_type(8)));

// ===========================================================================
// CSR build (bucketed, round-10 proven config)
// ===========================================================================
__global__ __launch_bounds__(256) void k_zero(int* __restrict__ p, int n) {
    for (int i = blockIdx.x * blockDim.x + threadIdx.x; i < n; i += gridDim.x * blockDim.x)
        p[i] = 0;
}

__global__ __launch_bounds__(256) void k_bucket_count(const int* __restrict__ rows,
                                                      int* __restrict__ bcnt, int E, int NBK) {
    __shared__ int h[NBK_MAX];
    for (int i = threadIdx.x; i < NBK; i += 256) h[i] = 0;
    __syncthreads();
    for (int e = blockIdx.x * blockDim.x + threadIdx.x; e < E; e += gridDim.x * blockDim.x)
        atomicAdd(&h[rows[e] >> SH], 1);
    __syncthreads();
    for (int i = threadIdx.x; i < NBK; i += 256) {
        int v = h[i];
        if (v) atomicAdd(&bcnt[i], v);
    }
}

// single block: exclusive scan of bucket counts + W->f16 fragment pack
__global__ __launch_bounds__(512) void k_scan_buckets(const int* __restrict__ bcnt,
                                                      int* __restrict__ boff,
                                                      int* __restrict__ bcur,
                                                      int* __restrict__ row_start,
                                                      int NBK, int N, int E,
                                                      const float* __restrict__ W,
                                                      f16x8* __restrict__ Whi) {
    __shared__ int sd[512];
    int t = threadIdx.x;
    int own = (t < NBK) ? bcnt[t] : 0;
    sd[t] = own;
    __syncthreads();
    for (int off = 1; off < 512; off <<= 1) {
        int add = (t >= off) ? sd[t - off] : 0;
        __syncthreads();
        sd[t] += add;
        __syncthreads();
    }
    if (t < NBK) {
        int ex = sd[t] - own;
        boff[t] = ex;
        bcur[t] = ex;
    }
    if (t == 0) {
        boff[NBK] = E;
        row_start[N] = E;
    }
    // W fragment pack (2048 fragments, 4 per thread), fused to save a launch
    if (Whi) {
#pragma unroll
        for (int u = 0; u < 4; ++u) {
            int f = t + u * 512;
            int l  = f & 63;
            int ks = (f >> 6) & 3;
            int ct = f >> 8;
            int o  = ct * 16 + (l & 15);
            int k0 = ks * 32 + ((l >> 4) * 8);
            const float* src = &W[o * D + k0];
            f16x8 hi;
#pragma unroll
            for (int i = 0; i < 8; ++i) hi[i] = (_Float16)src[i];
            Whi[f] = hi;
        }
    }
}

__global__ __launch_bounds__(256) void k_pairs(const int* __restrict__ rows,
                                               const int* __restrict__ cols,
                                               int* __restrict__ bcur,
                                               unsigned* __restrict__ pairs,
                                               int E, int NBK, int chunk) {
    __shared__ int h[NBK_MAX];
    int e0 = blockIdx.x * chunk;
    if (e0 >= E) return;
    int e1 = min(E, e0 + chunk);
    for (int i = threadIdx.x; i < NBK; i += 256) h[i] = 0;
    __syncthreads();
    for (int e = e0 + threadIdx.x; e < e1; e += 256)
        atomicAdd(&h[rows[e] >> SH], 1);
    __syncthreads();
    for (int b = threadIdx.x; b < NBK; b += 256) {
        int v = h[b];
        h[b] = v ? atomicAdd(&bcur[b], v) : 0;
    }
    __syncthreads();
    for (int e = e0 + threadIdx.x; e < e1; e += 256) {
        int r = rows[e];
        int b = r >> SH;
        int p = atomicAdd(&h[b], 1);
        pairs[p] = ((unsigned)(r & (BROWS - 1)) << 24) | (unsigned)cols[e];
    }
}

// per-bucket (256 rows, 256 threads): hist -> scan -> row_start/dr -> place
__global__ __launch_bounds__(256) void k_bucket_finish(const unsigned* __restrict__ pairs,
                                                       const int* __restrict__ boff,
                                                       int* __restrict__ row_start,
                                                       float* __restrict__ dr,
                                                       int* __restrict__ csr_col, int N) {
    __shared__ int h[BROWS];
    __shared__ int cur[BROWS];
    int b = blockIdx.x;
    int t = threadIdx.x;
    int lim = min(N - (b << SH), BROWS);
    h[t] = 0;
    __syncthreads();
    int p0 = boff[b], p1 = boff[b + 1];
    for (int p = p0 + t; p < p1; p += 256)
        atomicAdd(&h[pairs[p] >> 24], 1);
    __syncthreads();
    int own = h[t];
    cur[t] = own;
    __syncthreads();
    for (int off = 1; off < 256; off <<= 1) {
        int add = (t >= off) ? cur[t - off] : 0;
        __syncthreads();
        cur[t] += add;
        __syncthreads();
    }
    int rs = p0 + cur[t] - own;
    if (t < lim) {
        row_start[(b << SH) + t] = rs;
        dr[(b << SH) + t] = rsqrtf((float)(own + 1));
    }
    __syncthreads();
    cur[t] = rs;
    __syncthreads();
    for (int p = p0 + t; p < p1; p += 256) {
        unsigned v = pairs[p];
        int q = atomicAdd(&cur[v >> 24], 1);
        csr_col[q] = (int)(v & 0xFFFFFF);
    }
}

// x (fp32) -> xh (fp16), pre-scaled by dr (high-grid streaming kernel)
__global__ __launch_bounds__(256) void k_half_s(const float4* __restrict__ x4,
                                                const float* __restrict__ dr,
                                                f16x4* __restrict__ xh4, int n4) {
    for (int i = blockIdx.x * blockDim.x + threadIdx.x; i < n4; i += gridDim.x * blockDim.x) {
        float d = dr[i >> 5];   // 32 float4 per row
        float4 v = x4[i];
        xh4[i] = (f16x4){(_Float16)(v.x * d), (_Float16)(v.y * d),
                         (_Float16)(v.z * d), (_Float16)(v.w * d)};
    }
}

// ===========================================================================
// wide gather (round-12 measured 85 us): lane l = d-chunk (l&15)*8 of
// edge-slot l>>4; one f16x8 load covers 4 edges (1 KB/instr).
// agg f16 written into first 256 B of each 512 B out-row slot.
// ===========================================================================
__global__ __launch_bounds__(256) void k_gather_w(const int* __restrict__ row_start,
                                                  const int* __restrict__ csr_col,
                                                  const _Float16* __restrict__ xh,
                                                  const float* __restrict__ dr,
                                                  _Float16* __restrict__ aggh, int N) {
    int lane  = threadIdx.x & 63;
    int eslot = lane >> 4;          // 0..3
    int dbase = (lane & 15) * 8;    // half offset of this lane's d-chunk
    int gw = (blockIdx.x * blockDim.x + threadIdx.x) >> 6;
    int nw = (gridDim.x * blockDim.x) >> 6;
    for (int r = gw; r < N; r += nw) {
        int beg = row_start[r], end = row_start[r + 1];
        float drr = dr[r];
        float acc[8];
        if (eslot == 0) {
            f16x8 xs = *(const f16x8*)&xh[(size_t)r * D + dbase];
#pragma unroll
            for (int i = 0; i < 8; ++i) acc[i] = (float)xs[i];
        } else {
#pragma unroll
            for (int i = 0; i < 8; ++i) acc[i] = 0.f;
        }
        for (int cb = beg; cb < end; cb += 64) {
            int m = end - cb;
            if (m > 64) m = 64;
            int cidx = (lane < m) ? csr_col[cb + lane] : 0;
            int g = 0;
            for (; g + 16 <= m; g += 16) {
                int c0 = __shfl(cidx, g + eslot);
                int c1 = __shfl(cidx, g + 4 + eslot);
                int c2 = __shfl(cidx, g + 8 + eslot);
                int c3 = __shfl(cidx, g + 12 + eslot);
                f16x8 p0 = *(const f16x8*)&xh[(size_t)c0 * D + dbase];
                f16x8 p1 = *(const f16x8*)&xh[(size_t)c1 * D + dbase];
                f16x8 p2 = *(const f16x8*)&xh[(size_t)c2 * D + dbase];
                f16x8 p3 = *(const f16x8*)&xh[(size_t)c3 * D + dbase];
#pragma unroll
                for (int i = 0; i < 8; ++i)
                    acc[i] += ((float)p0[i] + (float)p1[i]) + ((float)p2[i] + (float)p3[i]);
            }
            for (; g < m; g += 4) {
                int srcl = g + eslot;
                bool valid = srcl < m;
                int c = __shfl(cidx, valid ? srcl : 0);
                if (valid) {
                    f16x8 pv = *(const f16x8*)&xh[(size_t)c * D + dbase];
#pragma unroll
                    for (int i = 0; i < 8; ++i) acc[i] += (float)pv[i];
                }
            }
        }
#pragma unroll
        for (int i = 0; i < 8; ++i) {
            acc[i] += __shfl_xor(acc[i], 16);
            acc[i] += __shfl_xor(acc[i], 32);
        }
        if (lane < 16) {
            f16x8 o;
#pragma unroll
            for (int i = 0; i < 8; ++i) o[i] = (_Float16)(drr * acc[i]);
            *(f16x8*)&aggh[(size_t)r * 256 + dbase] = o;
        }
    }
}

// ===========================================================================
// projection + relu: f16 MFMA (W single-f16), A from out slots, B from
// global L2-hot 32 KB; no LDS -> high occupancy. 32 MFMA / 16-row tile.
// ===========================================================================
__global__ __launch_bounds__(256) void k_project_g(const f16x8* __restrict__ Whi,
                                                   float* __restrict__ out, int N) {
    const _Float16* ah = (const _Float16*)out;
    int lane = threadIdx.x & 63;
    int wib  = threadIdx.x >> 6;
    int gw   = blockIdx.x * 4 + wib;
    int nw   = gridDim.x * 4;
    int nt   = N >> 4;
    int arow  = lane & 15;
    int kbase = (lane >> 4) * 8;

    for (int t = gw; t < nt; t += nw) {
        int row = t * 16 + arow;
        f16x8 A[KS];
#pragma unroll
        for (int ks = 0; ks < KS; ++ks)
            A[ks] = *(const f16x8*)&ah[(size_t)row * 256 + ks * 32 + kbase];

        f32x4 acc[CT];
#pragma unroll
        for (int ct = 0; ct < CT; ++ct) acc[ct] = (f32x4){0.f, 0.f, 0.f, 0.f};
#pragma unroll
        for (int ks = 0; ks < KS; ++ks) {
#pragma unroll
            for (int ct = 0; ct < CT; ++ct) {
                f16x8 bh = Whi[(ct * KS + ks) * 64 + lane];
                acc[ct] = __builtin_amdgcn_mfma_f32_16x16x32_f16(A[ks], bh, acc[ct], 0, 0, 0);
            }
        }
        int orow = t * 16 + (lane >> 4) * 4;
        int ocol = lane & 15;
#pragma unroll
        for (int ct = 0; ct < CT; ++ct) {
#pragma unroll
            for (int reg = 0; reg < 4; ++reg) {
                out[(size_t)(orow + reg) * D + ct * 16 + ocol] = fmaxf(acc[ct][reg], 0.f);
            }
        }
    }
}

// ===========================================================================
// mid-tier fallback: fp32 gather + LDS bf16-split project
// ===========================================================================
__global__ __launch_bounds__(256) void k_gather(const int* __restrict__ row_start,
                                                const int* __restrict__ csr_col,
                                                const float* __restrict__ x,
                                                const float* __restrict__ dr,
                                                float* __restrict__ out, int N) {
    int lane = threadIdx.x & 63;
    int gw = (blockIdx.x * blockDim.x + threadIdx.x) >> 6;
    int nw = (gridDim.x * blockDim.x) >> 6;
    for (int r = gw; r < N; r += nw) {
        float drr = dr[r];
        int beg = row_start[r], end = row_start[r + 1];
        const float2 xs = *(const float2*)&x[(size_t)r * D + lane * 2];
        float s = drr * drr;
        float a0 = s * xs.x, a1 = s * xs.y;
        for (int cb = beg; cb < end; cb += 64) {
            int m = end - cb;
            if (m > 64) m = 64;
            int   cidx = (lane < m) ? csr_col[cb + lane] : 0;
            float cdr  = (lane < m) ? dr[cidx] : 0.f;
            int j = 0;
            for (; j + 4 <= m; j += 4) {
                int c0 = __shfl(cidx, j);
                int c1 = __shfl(cidx, j + 1);
                int c2 = __shfl(cidx, j + 2);
                int c3 = __shfl(cidx, j + 3);
                float v0 = drr * __shfl(cdr, j);
                float v1 = drr * __shfl(cdr, j + 1);
                float v2 = drr * __shfl(cdr, j + 2);
                float v3 = drr * __shfl(cdr, j + 3);
                const float2 p0 = *(const float2*)&x[(size_t)c0 * D + lane * 2];
                const float2 p1 = *(const float2*)&x[(size_t)c1 * D + lane * 2];
                const float2 p2 = *(const float2*)&x[(size_t)c2 * D + lane * 2];
                const float2 p3 = *(const float2*)&x[(size_t)c3 * D + lane * 2];
                a0 = fmaf(v0, p0.x, a0); a1 = fmaf(v0, p0.y, a1);
                a0 = fmaf(v1, p1.x, a0); a1 = fmaf(v1, p1.y, a1);
                a0 = fmaf(v2, p2.x, a0); a1 = fmaf(v2, p2.y, a1);
                a0 = fmaf(v3, p3.x, a0); a1 = fmaf(v3, p3.y, a1);
            }
            for (; j < m; ++j) {
                int   c = __shfl(cidx, j);
                float v = drr * __shfl(cdr, j);
                const float2 p = *(const float2*)&x[(size_t)c * D + lane * 2];
                a0 = fmaf(v, p.x, a0);
                a1 = fmaf(v, p.y, a1);
            }
        }
        float2 o;
        o.x = a0;
        o.y = a1;
        *(float2*)&out[(size_t)r * D + lane * 2] = o;
    }
}

__global__ __launch_bounds__(256) void k_project_mfma(const float* __restrict__ W,
                                                      float* __restrict__ out, int N) {
    __shared__ bf16x8 Bhi[CT * KS * 64];
    __shared__ bf16x8 Blo[CT * KS * 64];
    for (int f = threadIdx.x; f < CT * KS * 64; f += 256) {
        int l  = f & 63;
        int ks = (f >> 6) & 3;
        int ct = f >> 8;
        int o  = ct * 16 + (l & 15);
        int k0 = ks * 32 + ((l >> 4) * 8);
        const float* src = &W[o * D + k0];
        bf16x8 hi, lo;
#pragma unroll
        for (int i = 0; i < 8; ++i) {
            float v  = src[i];
            __bf16 h = (__bf16)v;
            hi[i] = h;
            lo[i] = (__bf16)(v - (float)h);
        }
        Bhi[f] = hi;
        Blo[f] = lo;
    }
    __syncthreads();

    int lane = threadIdx.x & 63;
    int wib  = threadIdx.x >> 6;
    int gw   = blockIdx.x * 4 + wib;
    int nw   = gridDim.x * 4;
    int nt   = N >> 4;
    int arow  = lane & 15;
    int kbase = (lane >> 4) * 8;

    for (int t = gw; t < nt; t += nw) {
        int row = t * 16 + arow;
        const float* arp = &out[(size_t)row * D + kbase];
        bf16x8 Ahi[KS], Alo[KS];
#pragma unroll
        for (int ks = 0; ks < KS; ++ks) {
            float4 v0 = *(const float4*)&arp[ks * 32];
            float4 v1 = *(const float4*)&arp[ks * 32 + 4];
            float va[8] = {v0.x, v0.y, v0.z, v0.w, v1.x, v1.y, v1.z, v1.w};
            bf16x8 hi, lo;
#pragma unroll
            for (int i = 0; i < 8; ++i) {
                __bf16 h = (__bf16)va[i];
                hi[i] = h;
                lo[i] = (__bf16)(va[i] - (float)h);
            }
            Ahi[ks] = hi;
            Alo[ks] = lo;
        }
        f32x4 acc[CT];
#pragma unroll
        for (int ct = 0; ct < CT; ++ct) acc[ct] = (f32x4){0.f, 0.f, 0.f, 0.f};
#pragma unroll
        for (int ks = 0; ks < KS; ++ks) {
#pragma unroll
            for (int ct = 0; ct < CT; ++ct) {
                bf16x8 bh = Bhi[(ct * KS + ks) * 64 + lane];
                bf16x8 bl = Blo[(ct * KS + ks) * 64 + lane];
                acc[ct] = __builtin_amdgcn_mfma_f32_16x16x32_bf16(Ahi[ks], bh, acc[ct], 0, 0, 0);
                acc[ct] = __builtin_amdgcn_mfma_f32_16x16x32_bf16(Alo[ks], bh, acc[ct], 0, 0, 0);
                acc[ct] = __builtin_amdgcn_mfma_f32_16x16x32_bf16(Ahi[ks], bl, acc[ct], 0, 0, 0);
            }
        }
        int orow = t * 16 + (lane >> 4) * 4;
        int ocol = lane & 15;
#pragma unroll
        for (int ct = 0; ct < CT; ++ct) {
#pragma unroll
            for (int reg = 0; reg < 4; ++reg) {
                out[(size_t)(orow + reg) * D + ct * 16 + ocol] = fmaxf(acc[ct][reg], 0.f);
            }
        }
    }
}

// ===========================================================================
// last-resort fallback (atomic path)
// ===========================================================================
__global__ __launch_bounds__(256) void k_init_deg(int* __restrict__ deg, int n) {
    for (int i = blockIdx.x * blockDim.x + threadIdx.x; i < n; i += gridDim.x * blockDim.x)
        deg[i] = 1;
}
__global__ __launch_bounds__(256) void k_count_atomic(const int* __restrict__ rows,
                                                      int* __restrict__ cnt, int E) {
    for (int e = blockIdx.x * blockDim.x + threadIdx.x; e < E; e += gridDim.x * blockDim.x)
        atomicAdd(&cnt[rows[e]], 1);
}
__global__ __launch_bounds__(256) void k_rsqrt(float* __restrict__ buf, int n) {
    const int* di = (const int*)buf;
    for (int i = blockIdx.x * blockDim.x + threadIdx.x; i < n; i += gridDim.x * blockDim.x) {
        int v = di[i];
        buf[i] = rsqrtf((float)v);
    }
}
__global__ __launch_bounds__(256) void k_init_out(const float4* __restrict__ x4,
                                                  const float* __restrict__ dr,
                                                  float4* __restrict__ out4, int n4) {
    for (int i = blockIdx.x * blockDim.x + threadIdx.x; i < n4; i += gridDim.x * blockDim.x) {
        float d = dr[i >> 5];
        float s = d * d;
        float4 v = x4[i];
        out4[i] = make_float4(v.x * s, v.y * s, v.z * s, v.w * s);
    }
}
__global__ __launch_bounds__(256) void k_edges(const int* __restrict__ rows,
                                               const int* __restrict__ cols,
                                               const float* __restrict__ x,
                                               const float* __restrict__ dr,
                                               float* __restrict__ out, int E) {
    int lane = threadIdx.x & 63;
    int wib  = threadIdx.x >> 6;
    int gw   = blockIdx.x * 4 + wib;
    int nw   = gridDim.x * 4;
    for (int e = gw; e < E; e += nw) {
        int r = rows[e];
        int c = cols[e];
        float val = dr[r] * dr[c];
        const float2 xv = *(const float2*)&x[(size_t)c * D + lane * 2];
        float* po = &out[(size_t)r * D + lane * 2];
        unsafeAtomicAdd(po,     val * xv.x);
        unsafeAtomicAdd(po + 1, val * xv.y);
    }
}

// ===========================================================================
extern "C" void kernel_launch(void* const* d_in, const int* in_sizes, int n_in,
                              void* d_out, int out_size, void* d_ws, size_t ws_size,
                              hipStream_t stream) {
    const float* x   = (const float*)d_in[0];
    const int*   idx = (const int*)d_in[1];
    const float* W   = (const float*)d_in[2];
    float*       out = (float*)d_out;

    int N = in_sizes[0] / D;   // 100000
    int E = in_sizes[1] / 2;   // 1.6M
    const int* rows = idx;
    const int* cols = idx + E;

    int NBK = (N + BROWS - 1) >> SH;   // 391

    // workspace layout in 4B words
    size_t off = 0;
    size_t o_pairs = off;  off += (size_t)E;
    size_t o_csr   = off;  off += (size_t)E;
    size_t o_rs    = off;  off += (size_t)N + 1;
    size_t o_dr    = off;  off += (size_t)N;
    size_t o_bcnt  = off;  off += (size_t)NBK;
    size_t o_boff  = off;  off += (size_t)NBK + 1;
    size_t o_bcur  = off;  off += (size_t)NBK;
    off = (off + 3) & ~(size_t)3;      // 16B align
    size_t need_mid = off * 4;
    size_t o_whi   = off;  off += (size_t)(CT * KS * 64) * 4;   // f16x8 = 4 words
    size_t o_xh    = off;  off += ((size_t)N * D) / 2;          // halves = words/2
    size_t need_full = off * 4;

    int* wsw = (int*)d_ws;
    bool shape_ok = (NBK <= NBK_MAX) && ((N & 15) == 0) && (N < (1 << 24));

    if (shape_ok && ws_size >= need_mid) {
        unsigned* pairs     = (unsigned*)(wsw + o_pairs);
        int*      csr_col   = wsw + o_csr;
        int*      row_start = wsw + o_rs;
        float*    dr        = (float*)(wsw + o_dr);
        int*      bcnt      = wsw + o_bcnt;
        int*      boff      = wsw + o_boff;
        int*      bcur      = wsw + o_bcur;

        bool full = ws_size >= need_full;
        f16x8* Whi = full ? (f16x8*)(wsw + o_whi) : nullptr;

        const int CHUNK = 2048;        // 782 WGs in k_pairs
        k_zero<<<(NBK + 255) / 256, 256, 0, stream>>>(bcnt, NBK);
        k_bucket_count<<<512, 256, 0, stream>>>(rows, bcnt, E, NBK);
        k_scan_buckets<<<1, 512, 0, stream>>>(bcnt, boff, bcur, row_start, NBK, N, E, W, Whi);
        k_pairs<<<(E + CHUNK - 1) / CHUNK, 256, 0, stream>>>(rows, cols, bcur, pairs,
                                                             E, NBK, CHUNK);
        k_bucket_finish<<<NBK, 256, 0, stream>>>(pairs, boff, row_start, dr, csr_col, N);

        if (full) {
            _Float16* xh = (_Float16*)(wsw + o_xh);
            k_half_s<<<2048, 256, 0, stream>>>((const float4*)x, dr, (f16x4*)xh, N * (D / 4));
            _Float16* aggh = (_Float16*)out;
            k_gather_w<<<4096, 256, 0, stream>>>(row_start, csr_col, xh, dr, aggh, N);
            int nt = N >> 4;
            k_project_g<<<(nt + 3) / 4, 256, 0, stream>>>(Whi, out, N);
        } else {
            k_gather<<<4096, 256, 0, stream>>>(row_start, csr_col, x, dr, out, N);
            int nt = N >> 4;
            k_project_mfma<<<(nt + 3) / 4, 256, 0, stream>>>(W, out, N);
        }
    } else {
        int*   deg = (int*)d_ws;
        float* dr  = (float*)d_ws;
        k_init_deg<<<(N + 255) / 256, 256, 0, stream>>>(deg, N);
        k_count_atomic<<<2048, 256, 0, stream>>>(rows, deg, E);
        k_rsqrt<<<(N + 255) / 256, 256, 0, stream>>>(dr, N);
        int n4 = N * (D / 4);
        k_init_out<<<4096, 256, 0, stream>>>((const float4*)x, dr, (float4*)out, n4);
        k_edges<<<4096, 256, 0, stream>>>(rows, cols, x, dr, out, E);
        int nt = N >> 4;
        k_project_mfma<<<(nt + 3) / 4, 256, 0, stream>>>(W, out, N);
    }
}